// Round 1
// baseline (244.783 us; speedup 1.0000x reference)
//
#include <hip/hip_runtime.h>

// DifferentiableRankIntegration: B=1024, tau=0.1, K=60
// For each row r (independent):
//   sigma(a,b) = sigmoid((s[r,a]-s[r,b])/tau) = E_a / (E_a + E_b),  E = exp(s/tau)
//   rank_pos[b] = 1 + sum_a sigma(a,b)*nf[a]
//   rank_neg[b] = 1 + sum_a sigma(a,b)*pf[a]
//   rank[b]     = rank_pos[b]*pf[b] + rank_neg[b]*nf[b]
// S_hat = (K+1)*(w_v/(K+rank_v) + w_l/(K+rank_l))

constexpr int BDIM = 1024;
constexpr int NTHREADS = 256;
constexpr int CPT = BDIM / NTHREADS;  // columns per thread = 4

__global__ __launch_bounds__(NTHREADS, 2)
void rank_fused_kernel(const float* __restrict__ s_v,
                       const float* __restrict__ s_l,
                       const int* __restrict__ pos_mask,
                       const int* __restrict__ neg_mask,
                       const float* __restrict__ w_v,
                       const float* __restrict__ w_l,
                       float* __restrict__ out) {
    __shared__ float Ev[BDIM], Nv[BDIM], Pv[BDIM];
    __shared__ float El[BDIM], Nl[BDIM], Pl[BDIM];

    const int r = blockIdx.x;
    const int tid = threadIdx.x;
    // 1/(tau*ln2) = 10*log2(e)
    const float SCALE = 14.4269504088896340736f;

    // Stage per-row exp tables into LDS.
    for (int a = tid; a < BDIM; a += NTHREADS) {
        float xv = s_v[r * BDIM + a] * SCALE;
        float xl = s_l[r * BDIM + a] * SCALE;
        float ev = exp2f(xv);
        float el = exp2f(xl);
        float pf = (float)pos_mask[r * BDIM + a];
        float nf = (float)neg_mask[r * BDIM + a];
        Ev[a] = ev; Nv[a] = nf * ev; Pv[a] = pf * ev;
        El[a] = el; Nl[a] = nf * el; Pl[a] = pf * el;
    }
    __syncthreads();

    float aNv[CPT] = {0.f, 0.f, 0.f, 0.f};  // sum sigma_v * nf  -> rank_pos_v
    float aPv[CPT] = {0.f, 0.f, 0.f, 0.f};  // sum sigma_v * pf  -> rank_neg_v
    float aNl[CPT] = {0.f, 0.f, 0.f, 0.f};
    float aPl[CPT] = {0.f, 0.f, 0.f, 0.f};
    float ebv[CPT], ebl[CPT];
#pragma unroll
    for (int i = 0; i < CPT; ++i) {
        ebv[i] = Ev[tid + i * NTHREADS];
        ebl[i] = El[tid + i * NTHREADS];
    }

    for (int a0 = 0; a0 < BDIM; a0 += 4) {
        float4 e4v = *reinterpret_cast<const float4*>(&Ev[a0]);
        float4 n4v = *reinterpret_cast<const float4*>(&Nv[a0]);
        float4 p4v = *reinterpret_cast<const float4*>(&Pv[a0]);
        float4 e4l = *reinterpret_cast<const float4*>(&El[a0]);
        float4 n4l = *reinterpret_cast<const float4*>(&Nl[a0]);
        float4 p4l = *reinterpret_cast<const float4*>(&Pl[a0]);
        const float evs[4] = {e4v.x, e4v.y, e4v.z, e4v.w};
        const float nvs[4] = {n4v.x, n4v.y, n4v.z, n4v.w};
        const float pvs[4] = {p4v.x, p4v.y, p4v.z, p4v.w};
        const float els[4] = {e4l.x, e4l.y, e4l.z, e4l.w};
        const float nls[4] = {n4l.x, n4l.y, n4l.z, n4l.w};
        const float pls[4] = {p4l.x, p4l.y, p4l.z, p4l.w};
#pragma unroll
        for (int j = 0; j < 4; ++j) {
#pragma unroll
            for (int i = 0; i < CPT; ++i) {
                float rv = __builtin_amdgcn_rcpf(evs[j] + ebv[i]);
                aNv[i] = fmaf(nvs[j], rv, aNv[i]);
                aPv[i] = fmaf(pvs[j], rv, aPv[i]);
                float rl = __builtin_amdgcn_rcpf(els[j] + ebl[i]);
                aNl[i] = fmaf(nls[j], rl, aNl[i]);
                aPl[i] = fmaf(pls[j], rl, aPl[i]);
            }
        }
    }

#pragma unroll
    for (int i = 0; i < CPT; ++i) {
        int b = tid + i * NTHREADS;
        float pf = (float)pos_mask[r * BDIM + b];
        float nf = (float)neg_mask[r * BDIM + b];
        float rank_v = (1.0f + aNv[i]) * pf + (1.0f + aPv[i]) * nf;
        float rank_l = (1.0f + aNl[i]) * pf + (1.0f + aPl[i]) * nf;
        float wv = w_v[r * BDIM + b];
        float wl = w_l[r * BDIM + b];
        out[r * BDIM + b] =
            61.0f * (wv / (60.0f + rank_v) + wl / (60.0f + rank_l));
    }
}

extern "C" void kernel_launch(void* const* d_in, const int* in_sizes, int n_in,
                              void* d_out, int out_size, void* d_ws, size_t ws_size,
                              hipStream_t stream) {
    const float* s_v = (const float*)d_in[0];
    const float* s_l = (const float*)d_in[1];
    const int* pos_mask = (const int*)d_in[2];
    const int* neg_mask = (const int*)d_in[3];
    const float* w_v = (const float*)d_in[4];
    const float* w_l = (const float*)d_in[5];
    float* out = (float*)d_out;

    rank_fused_kernel<<<BDIM, NTHREADS, 0, stream>>>(s_v, s_l, pos_mask,
                                                     neg_mask, w_v, w_l, out);
}

// Round 3
// 179.492 us; speedup vs baseline: 1.3638x; 1.3638x over previous
//
#include <hip/hip_runtime.h>

// DifferentiableRankIntegration, B=1024, tau=0.1, K=60.
// sigma(a,b) = E_a/(E_a+E_b), E = exp2(s * log2(e)/tau).
// Category compaction: cat = pf | (nf<<1). Columns with cat==0 contribute
// nothing as 'a' and have rank==0 as 'b'. cat3 columns feed ONE combined
// accumulator (their sigma goes to both rank_pos and rank_neg sums).
//   AN[b] (= sum sigma*nf -> rank_pos) = S3 + S2
//   AP[b] (= sum sigma*pf -> rank_neg) = S3 + S1
// rank = (1+AN)*pf_b + (1+AP)*nf_b ; out = 61*(wv/(60+rk_v)+wl/(60+rk_l)).

constexpr int B = 1024;
constexpr int NT = 256;
constexpr int SLOTS = 1104;  // 1024 + seg pads (<=9) + 64-pad (<=63), 16B mult
constexpr int DUMP = 1024;   // garbage sink index for dummy slots

__global__ __launch_bounds__(NT, 2)
void rank_cat_kernel(const float* __restrict__ s_v,
                     const float* __restrict__ s_l,
                     const int* __restrict__ pos_m,
                     const int* __restrict__ neg_m,
                     const float* __restrict__ w_v,
                     const float* __restrict__ w_l,
                     float* __restrict__ out) {
    __shared__ __align__(16) float EcV[SLOTS];   // compacted E (v), dummies = 0
    __shared__ __align__(16) float EcL[SLOTS];   // compacted E (l)
    __shared__ int Idx[SLOTS];                   // compacted slot -> orig column
    __shared__ float A[4][1028];                 // ANv, APv, ANl, APl by orig col
    __shared__ int segCnt[3][16];                // [cat-1][unit], unit = i*4+wave

    const int r = blockIdx.x;
    const int tid = threadIdx.x;
    const int lane = tid & 63;
    const int wvid = tid >> 6;
    const float SCALE = 14.4269504088896340736f;  // log2(e)/tau

    for (int s = tid; s < SLOTS; s += NT) { EcV[s] = 0.f; EcL[s] = 0.f; Idx[s] = DUMP; }
    __syncthreads();

    // ---- Phase 1: read, categorize, ballot-count (deterministic) ----
    int cat[4]; int myrank[4]; float ev[4], el[4];
#pragma unroll
    for (int i = 0; i < 4; ++i) {
        const int c = tid + i * NT;
        const float svi = s_v[r * B + c];
        const float sli = s_l[r * B + c];
        const int pf = pos_m[r * B + c] != 0;
        const int nf = neg_m[r * B + c] != 0;
        cat[i] = pf | (nf << 1);
        ev[i] = exp2f(svi * SCALE);
        el[i] = exp2f(sli * SCALE);
        myrank[i] = 0;
#pragma unroll
        for (int k = 1; k <= 3; ++k) {
            unsigned long long m = __ballot(cat[i] == k);
            if (cat[i] == k) myrank[i] = __popcll(m & ((1ull << lane) - 1ull));
            if (lane == 0) segCnt[k - 1][i * 4 + wvid] = (int)__popcll(m);
        }
    }
    __syncthreads();

    int n1 = 0, n2 = 0, n3 = 0;
#pragma unroll
    for (int u = 0; u < 16; ++u) {
        n1 += segCnt[0][u]; n2 += segCnt[1][u]; n3 += segCnt[2][u];
    }
    const int p3 = (n3 + 3) & ~3;   // segment lengths padded to float4
    const int p2 = (n2 + 3) & ~3;
    const int p1 = (n1 + 3) & ~3;
    const int b3 = 0, b2 = p3, b1 = p3 + p2;
    const int na64 = (b1 + p1 + 63) & ~63;  // active b-slot bound, wave-uniform

    // ---- Phase 2: deterministic placement ----
#pragma unroll
    for (int i = 0; i < 4; ++i) {
        if (cat[i]) {
            const int k = cat[i];
            const int unit = i * 4 + wvid;
            int pre = 0;
            for (int u = 0; u < unit; ++u) pre += segCnt[k - 1][u];
            const int base = (k == 3) ? b3 : (k == 2) ? b2 : b1;
            const int slot = base + pre + myrank[i];
            EcV[slot] = ev[i];
            EcL[slot] = el[i];
            Idx[slot] = tid + i * NT;
        }
    }
    __syncthreads();

    // ---- Main loop: per own compacted slot, sum over the 3 active segments ----
    float ANv[4], APv[4], ANl[4], APl[4];

    auto segsum2 = [&](int base, int pcnt, float ebv, float ebl,
                       float& Sv, float& Sl) {
        for (int j = 0; j < pcnt; j += 4) {
            const float4 a4 = *(const float4*)&EcV[base + j];
            const float4 c4 = *(const float4*)&EcL[base + j];
            Sv = fmaf(a4.x, __builtin_amdgcn_rcpf(a4.x + ebv), Sv);
            Sv = fmaf(a4.y, __builtin_amdgcn_rcpf(a4.y + ebv), Sv);
            Sv = fmaf(a4.z, __builtin_amdgcn_rcpf(a4.z + ebv), Sv);
            Sv = fmaf(a4.w, __builtin_amdgcn_rcpf(a4.w + ebv), Sv);
            Sl = fmaf(c4.x, __builtin_amdgcn_rcpf(c4.x + ebl), Sl);
            Sl = fmaf(c4.y, __builtin_amdgcn_rcpf(c4.y + ebl), Sl);
            Sl = fmaf(c4.z, __builtin_amdgcn_rcpf(c4.z + ebl), Sl);
            Sl = fmaf(c4.w, __builtin_amdgcn_rcpf(c4.w + ebl), Sl);
        }
    };

#pragma unroll
    for (int i = 0; i < 4; ++i) {
        const int slot = tid + i * NT;
        float S3v = 0.f, S2v = 0.f, S1v = 0.f;
        float S3l = 0.f, S2l = 0.f, S1l = 0.f;
        if (slot < na64) {   // wave-uniform guard (na64 is a multiple of 64)
            const float ebv = EcV[slot];
            const float ebl = EcL[slot];
            segsum2(b3, p3, ebv, ebl, S3v, S3l);
            segsum2(b2, p2, ebv, ebl, S2v, S2l);
            segsum2(b1, p1, ebv, ebl, S1v, S1l);
        }
        ANv[i] = S3v + S2v; APv[i] = S3v + S1v;
        ANl[i] = S3l + S2l; APl[i] = S3l + S1l;
    }

    // ---- Un-scatter ranks to original column order, then coalesced epilogue ----
#pragma unroll
    for (int i = 0; i < 4; ++i) {
        const int oi = Idx[tid + i * NT];   // dummy slots -> DUMP (never read)
        A[0][oi] = ANv[i];
        A[1][oi] = APv[i];
        A[2][oi] = ANl[i];
        A[3][oi] = APl[i];
    }
    __syncthreads();

#pragma unroll
    for (int i = 0; i < 4; ++i) {
        const int c = tid + i * NT;
        const bool pf = (cat[i] & 1) != 0;
        const bool nf = (cat[i] & 2) != 0;
        // selects (not multiplies) so uninitialized A[] for cat0 cols never leaks
        const float rkv = (pf ? 1.f + A[0][c] : 0.f) + (nf ? 1.f + A[1][c] : 0.f);
        const float rkl = (pf ? 1.f + A[2][c] : 0.f) + (nf ? 1.f + A[3][c] : 0.f);
        out[r * B + c] = 61.f * (w_v[r * B + c] / (60.f + rkv) +
                                 w_l[r * B + c] / (60.f + rkl));
    }
}

extern "C" void kernel_launch(void* const* d_in, const int* in_sizes, int n_in,
                              void* d_out, int out_size, void* d_ws, size_t ws_size,
                              hipStream_t stream) {
    const float* s_v = (const float*)d_in[0];
    const float* s_l = (const float*)d_in[1];
    const int* pos_mask = (const int*)d_in[2];
    const int* neg_mask = (const int*)d_in[3];
    const float* w_v = (const float*)d_in[4];
    const float* w_l = (const float*)d_in[5];
    float* out = (float*)d_out;

    rank_cat_kernel<<<B, NT, 0, stream>>>(s_v, s_l, pos_mask, neg_mask,
                                          w_v, w_l, out);
}

// Round 4
// 115.869 us; speedup vs baseline: 2.1126x; 1.5491x over previous
//
#include <hip/hip_runtime.h>

// DifferentiableRankIntegration, B=1024, tau=0.1, K=60.
// sigma(a,b) = E_a/(E_a+E_b), E = exp2(clamp(s*log2(e)/tau, +-60)).
// Category compaction (cat = pf | nf<<1); cat0 columns skipped both sides.
// Pair-combining (exact algebra): for a-pair with S=E1+E2, P=E1*E2:
//   sigma1+sigma2 = (2P + S x)/(P + S x + x^2),  x = E_b
// -> per 2 ordered pair-matrix terms: q=fma(S,x,P); n=q+P; d=q+xx;
//    acc=fma(n,rcp(d),acc)  (4 VALU + 1 trans).
// Mixed real/dummy pair (E2=0): S=E1,P=0 -> (E1 x)/(E1 x + x^2) = E1/(E1+x) exact.
//   AN[b](rank_pos sum) = S3+S2 ; AP[b](rank_neg sum) = S3+S1
// rank = (1+AN)*pf_b + (1+AP)*nf_b ; out = 61*(wv/(60+rk_v)+wl/(60+rk_l)).

constexpr int B = 1024;
constexpr int NT = 256;
constexpr int SLOTS = 1088;     // ceil64(1024 + 3*7) ; >= na64 always
constexpr int NPAIR = SLOTS/2;  // 544
constexpr int DUMP = 1024;      // garbage sink for dummy slots

__global__ __launch_bounds__(NT, 2)
void rank_pair_kernel(const float* __restrict__ s_v,
                      const float* __restrict__ s_l,
                      const int* __restrict__ pos_m,
                      const int* __restrict__ neg_m,
                      const float* __restrict__ w_v,
                      const float* __restrict__ w_l,
                      float* __restrict__ out) {
    __shared__ __align__(16) float EcV[SLOTS], EcL[SLOTS];  // compacted E, dummies=0
    __shared__ __align__(16) float SSv[NPAIR], PPv[NPAIR];  // pair sums/products
    __shared__ __align__(16) float SSl[NPAIR], PPl[NPAIR];
    __shared__ int Idx[SLOTS];       // compacted slot -> orig column
    __shared__ float A[4][1028];     // ANv, APv, ANl, APl by orig column
    __shared__ int segCnt[3][16];    // [cat-1][unit], unit = i*4 + wave

    const int r = blockIdx.x;
    const int tid = threadIdx.x;
    const int lane = tid & 63;
    const int wvid = tid >> 6;
    const float SCALE = 14.4269504088896340736f;  // log2(e)/tau

    for (int s = tid; s < SLOTS; s += NT) { EcV[s] = 0.f; EcL[s] = 0.f; Idx[s] = DUMP; }
    __syncthreads();

    // ---- Phase 1: read, categorize, ballot-count ----
    int cat[4]; int myrank[4]; float ev[4], el[4];
#pragma unroll
    for (int i = 0; i < 4; ++i) {
        const int c = tid + i * NT;
        float uv = s_v[r * B + c] * SCALE;
        float ul = s_l[r * B + c] * SCALE;
        uv = fminf(fmaxf(uv, -60.f), 60.f);   // overflow guard for P = E1*E2
        ul = fminf(fmaxf(ul, -60.f), 60.f);
        ev[i] = exp2f(uv);
        el[i] = exp2f(ul);
        const int pf = pos_m[r * B + c] != 0;
        const int nf = neg_m[r * B + c] != 0;
        cat[i] = pf | (nf << 1);
        myrank[i] = 0;
#pragma unroll
        for (int k = 1; k <= 3; ++k) {
            unsigned long long m = __ballot(cat[i] == k);
            if (cat[i] == k) myrank[i] = __popcll(m & ((1ull << lane) - 1ull));
            if (lane == 0) segCnt[k - 1][i * 4 + wvid] = (int)__popcll(m);
        }
    }
    __syncthreads();

    int n1 = 0, n2 = 0, n3 = 0;
#pragma unroll
    for (int u = 0; u < 16; ++u) {
        n1 += segCnt[0][u]; n2 += segCnt[1][u]; n3 += segCnt[2][u];
    }
    const int p3 = (n3 + 7) & ~7;   // segments padded to 8 slots (4 pairs)
    const int p2 = (n2 + 7) & ~7;
    const int p1 = (n1 + 7) & ~7;
    const int b2 = p3, b1 = p3 + p2;
    const int na64 = (b1 + p1 + 63) & ~63;  // active b bound (mult of 64; ~832 here)

    // ---- Phase 2: deterministic placement ----
#pragma unroll
    for (int i = 0; i < 4; ++i) {
        if (cat[i]) {
            const int k = cat[i];
            const int unit = i * 4 + wvid;
            int pre = 0;
            for (int u = 0; u < unit; ++u) pre += segCnt[k - 1][u];
            const int base = (k == 3) ? 0 : (k == 2) ? b2 : b1;
            const int slot = base + pre + myrank[i];
            EcV[slot] = ev[i]; EcL[slot] = el[i]; Idx[slot] = tid + i * NT;
        }
    }
    __syncthreads();

    // ---- Phase 2.5: build pair (S,P) tables ----
    for (int j = tid; j < NPAIR; j += NT) {
        float a0 = EcV[2 * j], a1 = EcV[2 * j + 1];
        SSv[j] = a0 + a1; PPv[j] = a0 * a1;
        float c0 = EcL[2 * j], c1 = EcL[2 * j + 1];
        SSl[j] = c0 + c1; PPl[j] = c0 * c1;
    }
    __syncthreads();

    // ---- Main loop: 4 consecutive b-slots per thread, pairs broadcast from LDS ----
    float a3v[4] = {0,0,0,0}, a2v[4] = {0,0,0,0}, a1v[4] = {0,0,0,0};
    float a3l[4] = {0,0,0,0}, a2l[4] = {0,0,0,0}, a1l[4] = {0,0,0,0};

    const int s0 = 4 * tid;
    if (s0 < na64) {     // lane cutoff is a multiple of 16 -> benign divergence
        const float4 x4v = *(const float4*)&EcV[s0];
        const float4 x4l = *(const float4*)&EcL[s0];
        const float xv[4] = {x4v.x, x4v.y, x4v.z, x4v.w};
        const float xl[4] = {x4l.x, x4l.y, x4l.z, x4l.w};
        float xxv[4], xxl[4];
#pragma unroll
        for (int i = 0; i < 4; ++i) {
            xxv[i] = fmaf(xv[i], xv[i], 1e-33f);  // eps: den>0 so rcp finite
            xxl[i] = fmaf(xl[i], xl[i], 1e-33f);
        }

        auto segsum = [&](int pb, int pc, float accv[4], float accl[4]) {
            for (int pj = pb; pj < pb + pc; pj += 4) {
                const float4 s4v = *(const float4*)&SSv[pj];
                const float4 p4v = *(const float4*)&PPv[pj];
                const float4 s4l = *(const float4*)&SSl[pj];
                const float4 p4l = *(const float4*)&PPl[pj];
                const float sv[4] = {s4v.x, s4v.y, s4v.z, s4v.w};
                const float pv[4] = {p4v.x, p4v.y, p4v.z, p4v.w};
                const float sl[4] = {s4l.x, s4l.y, s4l.z, s4l.w};
                const float pl[4] = {p4l.x, p4l.y, p4l.z, p4l.w};
#pragma unroll
                for (int e = 0; e < 4; ++e) {
#pragma unroll
                    for (int i = 0; i < 4; ++i) {
                        float q = fmaf(sv[e], xv[i], pv[e]);
                        float n = q + pv[e];
                        float d = q + xxv[i];
                        accv[i] = fmaf(n, __builtin_amdgcn_rcpf(d), accv[i]);
                        float ql = fmaf(sl[e], xl[i], pl[e]);
                        float nl = ql + pl[e];
                        float dl = ql + xxl[i];
                        accl[i] = fmaf(nl, __builtin_amdgcn_rcpf(dl), accl[i]);
                    }
                }
            }
        };
        segsum(0, p3 >> 1, a3v, a3l);
        segsum(b2 >> 1, p2 >> 1, a2v, a2l);
        segsum(b1 >> 1, p1 >> 1, a1v, a1l);
    }

    // ---- Un-scatter ranks to original order ----
#pragma unroll
    for (int i = 0; i < 4; ++i) {
        const int oi = Idx[s0 + i];         // dummy/inactive -> DUMP
        A[0][oi] = a3v[i] + a2v[i];         // ANv
        A[1][oi] = a3v[i] + a1v[i];         // APv
        A[2][oi] = a3l[i] + a2l[i];         // ANl
        A[3][oi] = a3l[i] + a1l[i];         // APl
    }
    __syncthreads();

    // ---- Coalesced epilogue ----
#pragma unroll
    for (int i = 0; i < 4; ++i) {
        const int c = tid + i * NT;
        const bool pf = (cat[i] & 1) != 0;
        const bool nf = (cat[i] & 2) != 0;
        const float rkv = (pf ? 1.f + A[0][c] : 0.f) + (nf ? 1.f + A[1][c] : 0.f);
        const float rkl = (pf ? 1.f + A[2][c] : 0.f) + (nf ? 1.f + A[3][c] : 0.f);
        out[r * B + c] = 61.f * (w_v[r * B + c] / (60.f + rkv) +
                                 w_l[r * B + c] / (60.f + rkl));
    }
}

extern "C" void kernel_launch(void* const* d_in, const int* in_sizes, int n_in,
                              void* d_out, int out_size, void* d_ws, size_t ws_size,
                              hipStream_t stream) {
    const float* s_v = (const float*)d_in[0];
    const float* s_l = (const float*)d_in[1];
    const int* pos_mask = (const int*)d_in[2];
    const int* neg_mask = (const int*)d_in[3];
    const float* w_v = (const float*)d_in[4];
    const float* w_l = (const float*)d_in[5];
    float* out = (float*)d_out;

    rank_pair_kernel<<<B, NT, 0, stream>>>(s_v, s_l, pos_mask, neg_mask,
                                           w_v, w_l, out);
}